// Round 2
// baseline (190.252 us; speedup 1.0000x reference)
//
#include <hip/hip_runtime.h>

// SobelLoss: mean over 3 dirs of mean |sobel(moved) - sobel(label)|.
// conv(m)-conv(l) = conv(m-l); separable sobel: s=[1,2,1], d=[-1,0,1]:
//   gx = sD*sH*dW, gy = sD*dH*sW, gz = -dD*sH*sW.
// One pass over D with rolling 3-plane register window; one LDS plane
// (double-buffered). R2: float4 staging loads, register prefetch pipeline,
// DC=5 -> 1536 blocks (6 blocks/CU, 24 waves/CU).

#define BB 2
#define DD 160
#define HH 192
#define WW 160
#define HW (HH * WW)

#define TH 8            // H rows per block
#define DC 5            // D slices per block
#define PSTRIDE 168     // row stride in LDS floats; interior at [4..163], zero halo at 3 & 164
#define PROWS   (TH + 2)
#define NTHREADS 256
#define WPT 5           // outputs per thread along W (32 groups * 5 = 160)
#define QPR (WW / 4)    // float4 quads per row = 40
#define NITEMS (PROWS * QPR)   // 400 quads per plane per array

__global__ __launch_bounds__(NTHREADS, 6) void sobel_loss_kernel(
    const float* __restrict__ moved, const float* __restrict__ label,
    float* __restrict__ out)
{
    __shared__ float plane[2][PROWS * PSTRIDE];
    __shared__ float red[NTHREADS / 64];

    const int tid = threadIdx.x;
    const int h0  = blockIdx.x * TH;   // 24 tiles
    const int d0  = blockIdx.y * DC;   // 32 chunks
    const int b   = blockIdx.z;        // 2
    const int base_b = b * (DD * HW);  // < 2^31

    // ---- staging item descriptors (2 float4-quads per thread, 400 total) ----
    const int i0 = tid;                 // always valid (400 > 256)
    const int i1 = tid + NTHREADS;      // valid if < 400
    const int r0i = i0 / QPR, q0 = i0 - r0i * QPR;
    const int r1i = i1 / QPR, q1 = i1 - r1i * QPR;
    const int gh0 = h0 + r0i - 1, gh1 = h0 + r1i - 1;
    const bool hv0 = (unsigned)gh0 < (unsigned)HH;
    const bool st1 = i1 < NITEMS;
    const bool hv1 = st1 && ((unsigned)gh1 < (unsigned)HH);
    const int go0 = base_b + gh0 * WW + 4 * q0;      // + p*HW at use
    const int go1 = base_b + gh1 * WW + 4 * q1;
    const int lo0 = r0i * PSTRIDE + 4 + 4 * q0;      // 16B-aligned LDS offsets
    const int lo1 = r1i * PSTRIDE + 4 + 4 * q1;

    // ---- zero the W-halo columns (never touched by staging writes) ----
    if (tid < PROWS * 2) {
        const int r = tid >> 1;
        const int c = (tid & 1) ? (4 + WW) : 3;
        plane[0][r * PSTRIDE + c] = 0.f;
        plane[1][r * PSTRIDE + c] = 0.f;
    }

    // ---- compute mapping: 8 h-rows x 32 w-groups of 5 ----
    const int hl    = tid >> 5;
    const int wbase = (tid & 31) * WPT;

    float4 m0, l0, m1, l1;
    {   // prefetch first plane (d0-1)
        const int p = d0 - 1;
        const bool pin = (unsigned)p < (unsigned)DD;
        const int pb = p * HW;
        m0 = l0 = m1 = l1 = make_float4(0.f, 0.f, 0.f, 0.f);
        if (pin && hv0) { m0 = *(const float4*)(moved + pb + go0);
                          l0 = *(const float4*)(label + pb + go0); }
        if (pin && hv1) { m1 = *(const float4*)(moved + pb + go1);
                          l1 = *(const float4*)(label + pb + go1); }
    }

    float pxm1[WPT], pxm2[WPT], pym1[WPT], pym2[WPT], pzm1[WPT], pzm2[WPT];
#pragma unroll
    for (int k = 0; k < WPT; ++k) {
        pxm1[k] = pxm2[k] = 0.f;
        pym1[k] = pym2[k] = 0.f;
        pzm1[k] = pzm2[k] = 0.f;
    }

    float acc = 0.f;

    for (int it = 0; it < DC + 2; ++it) {
        float* buf = plane[it & 1];

        // ---- commit current plane's diff to LDS (waits the inflight loads) --
        float4 dA = make_float4(m0.x - l0.x, m0.y - l0.y, m0.z - l0.z, m0.w - l0.w);
        float4 dB = make_float4(m1.x - l1.x, m1.y - l1.y, m1.z - l1.z, m1.w - l1.w);
        *(float4*)(buf + lo0) = dA;
        if (st1) *(float4*)(buf + lo1) = dB;

        // ---- issue next plane's loads; they fly during compute below ----
        if (it < DC + 1) {
            const int p = d0 + it;     // plane of iteration it+1
            const bool pin = (unsigned)p < (unsigned)DD;
            const int pb = p * HW;
            m0 = l0 = m1 = l1 = make_float4(0.f, 0.f, 0.f, 0.f);
            if (pin && hv0) { m0 = *(const float4*)(moved + pb + go0);
                              l0 = *(const float4*)(label + pb + go0); }
            if (pin && hv1) { m1 = *(const float4*)(moved + pb + go1);
                              l1 = *(const float4*)(label + pb + go1); }
        }

        __syncthreads();
        // single sync/iter: write(it) into buf[it&1] is after sync(it-1), which
        // every thread passes only after finishing compute(it-2) on this buffer.

        // ---- per-plane separable partials ----
        const float* r0 = buf + hl * PSTRIDE + 3 + wbase;   // row gh = h-1
        const float* r1 = r0 + PSTRIDE;                      // h
        const float* r2 = r1 + PSTRIDE;                      // h+1
        float cS[WPT + 2], cD[WPT + 2];
#pragma unroll
        for (int x = 0; x < WPT + 2; ++x) {
            const float a = r0[x], m = r1[x], c2 = r2[x];
            cS[x] = (a + c2) + 2.f * m;   // smooth over H
            cD[x] = c2 - a;               // deriv  over H
        }
#pragma unroll
        for (int k = 0; k < WPT; ++k) {
            const float px = cS[k + 2] - cS[k];                     // dW sH
            const float pz = (cS[k] + cS[k + 2]) + 2.f * cS[k + 1]; // sW sH
            const float py = (cD[k] + cD[k + 2]) + 2.f * cD[k + 1]; // sW dH
            if (it >= 2) {
                const float gx = pxm2[k] + 2.f * pxm1[k] + px;  // sD
                const float gy = pym2[k] + 2.f * pym1[k] + py;  // sD
                const float gz = pzm2[k] - pz;                  // dD: (d-1)-(d+1)
                acc += fabsf(gx) + fabsf(gy) + fabsf(gz);
            }
            pxm2[k] = pxm1[k]; pxm1[k] = px;
            pym2[k] = pym1[k]; pym1[k] = py;
            pzm2[k] = pzm1[k]; pzm1[k] = pz;
        }
    }

    // ---- reduce: wave shuffle -> LDS -> one atomic per block ----
#pragma unroll
    for (int off = 32; off > 0; off >>= 1)
        acc += __shfl_down(acc, off, 64);
    if ((tid & 63) == 0) red[tid >> 6] = acc;
    __syncthreads();
    if (tid == 0) {
        const float s = red[0] + red[1] + red[2] + red[3];
        atomicAdd(out, s * (1.0f / (3.0f * BB * DD * HH * WW)));
    }
}

extern "C" void kernel_launch(void* const* d_in, const int* in_sizes, int n_in,
                              void* d_out, int out_size, void* d_ws, size_t ws_size,
                              hipStream_t stream) {
    const float* moved = (const float*)d_in[0];
    const float* label = (const float*)d_in[1];
    float* out = (float*)d_out;
    (void)in_sizes; (void)n_in; (void)out_size; (void)d_ws; (void)ws_size;

    hipMemsetAsync(out, 0, sizeof(float), stream);
    dim3 grid(HH / TH, DD / DC, BB);    // 24 x 32 x 2 = 1536 blocks
    sobel_loss_kernel<<<grid, NTHREADS, 0, stream>>>(moved, label, out);
}

// Round 3
// 120.278 us; speedup vs baseline: 1.5818x; 1.5818x over previous
//
#include <hip/hip_runtime.h>
#include <stdint.h>

// SobelLoss: mean over 3 dirs of mean |sobel(moved) - sobel(label)|.
// conv(m)-conv(l) = conv(m-l); separable: s=[1,2,1], d=[-1,0,1]:
//   gx = sD*sH*dW, gy = sD*dH*sW, gz = -dD*sH*sW.
// R3: global->LDS DMA staging (no VGPR round-trip; R2's VGPR prefetch spilled
// to scratch: 198 MB WRITE_SIZE), triple-buffered plane pipeline, boundary
// zero-padding via predication (DMA needs lane-contiguous LDS, no pad halos).

#define BB 2
#define DD 160
#define HH 192
#define WW 160
#define HW (HH * WW)
#define NTOT (BB * DD * HW)

#define TH 8                    // H rows per block
#define DC 10                   // D slices per block
#define NIT (DC + 2)
#define PROWS (TH + 2)          // 10
#define PFLOATS (PROWS * WW)    // 1600 floats per plane tile
#define PPAD 1792               // 448 quads = 7 full wave-rounds of 64x16B
#define NTHREADS 256
#define WPT 5                   // 32 w-groups * 5 = 160

#define AS1 __attribute__((address_space(1)))
#define AS3 __attribute__((address_space(3)))

__device__ __forceinline__ void dma16(const float* g, float* l) {
    __builtin_amdgcn_global_load_lds((const AS1 void*)g, (AS3 void*)l, 16, 0, 0);
}

__global__ __launch_bounds__(NTHREADS) void sobel_loss_kernel(
    const float* __restrict__ moved, const float* __restrict__ label,
    float* __restrict__ out)
{
    __shared__ float sm[3][PPAD];   // raw moved planes
    __shared__ float sl[3][PPAD];   // raw label planes
    __shared__ float red[NTHREADS / 64];

    const int tid = threadIdx.x;
    const int h0  = blockIdx.x * TH;   // 24 tiles
    const int d0  = blockIdx.y * DC;   // 16 chunks
    const int b   = blockIdx.z;        // 2
    const int base_b = b * (DD * HW);

    // per-thread DMA descriptors: quad q0=tid (all), q1=tid+256 (waves 0..2)
    const bool do2 = (tid < 192);      // 448 quads total; wave-uniform predicate

    // compute mapping: 8 h-rows x 32 w-groups of 5
    const int hl    = tid >> 5;
    const int wbase = (tid & 31) * WPT;

    // row validity (independent of plane): local rows hl, hl+1, hl+2
    const bool rv0 = (h0 + hl) > 0;                 // gh = h0+hl-1 >= 0
    const bool rv2 = (h0 + hl + 1) < HH;            // gh = h0+hl+1 <= 191

    // stage plane pl into slot s (raw copy, garbage outside valid range)
    auto stage = [&](int pl, int s) {
        if ((unsigned)pl >= (unsigned)DD) return;   // whole plane masked later
        const int pstart = base_b + pl * HW + (h0 - 1) * WW;  // float idx of lds[0]
        int g0 = pstart + tid * 4;
        g0 = min(max(g0, 0), NTOT - 4);             // stay inside allocation
        dma16(moved + g0, &sm[s][tid * 4]);
        dma16(label + g0, &sl[s][tid * 4]);
        if (do2) {
            int g1 = pstart + (tid + NTHREADS) * 4;
            g1 = min(max(g1, 0), NTOT - 4);
            dma16(moved + g1, &sm[s][(tid + NTHREADS) * 4]);
            dma16(label + g1, &sl[s][(tid + NTHREADS) * 4]);
        }
    };

    float pxm1[WPT], pxm2[WPT], pym1[WPT], pym2[WPT], pzm1[WPT], pzm2[WPT];
#pragma unroll
    for (int k = 0; k < WPT; ++k) {
        pxm1[k] = pxm2[k] = 0.f;
        pym1[k] = pym2[k] = 0.f;
        pzm1[k] = pzm2[k] = 0.f;
    }
    float acc = 0.f;

    stage(d0 - 1, 0);
    stage(d0,     1);
    __syncthreads();   // barrier drains vmcnt: both planes landed

    for (int it = 0; it < NIT; ++it) {
        // issue next-next plane's DMA; flies during this compute phase,
        // drained by the barrier below. slot (it+2)%3 == (it-1)%3 was last
        // read at iter it-1, whose readers passed the previous barrier.
        if (it + 2 < NIT) stage(d0 - 1 + (it + 2), (it + 2) % 3);

        const int s = it % 3;
        const float* mb = sm[s];
        const float* lb = sl[s];
        const bool pv = (unsigned)(d0 - 1 + it) < (unsigned)DD;

        const bool v0 = pv && rv0;
        const bool v1 = pv;
        const bool v2 = pv && rv2;
        const int o0 = hl * WW;
        const int o1 = o0 + WW;
        const int o2 = o1 + WW;

        float cS[WPT + 2], cD[WPT + 2];
#pragma unroll
        for (int x = 0; x < WPT + 2; ++x) {
            const int w  = wbase - 1 + x;
            const bool wv = (unsigned)w < (unsigned)WW;
            const int wc = wv ? w : (w < 0 ? 0 : WW - 1);   // clamped LDS index
            const float a  = (v0 && wv) ? (mb[o0 + wc] - lb[o0 + wc]) : 0.f;
            const float m  = (v1 && wv) ? (mb[o1 + wc] - lb[o1 + wc]) : 0.f;
            const float c2 = (v2 && wv) ? (mb[o2 + wc] - lb[o2 + wc]) : 0.f;
            cS[x] = (a + c2) + 2.f * m;   // smooth over H
            cD[x] = c2 - a;               // deriv  over H
        }
#pragma unroll
        for (int k = 0; k < WPT; ++k) {
            const float px = cS[k + 2] - cS[k];                     // dW sH
            const float pz = (cS[k] + cS[k + 2]) + 2.f * cS[k + 1]; // sW sH
            const float py = (cD[k] + cD[k + 2]) + 2.f * cD[k + 1]; // sW dH
            if (it >= 2) {
                const float gx = pxm2[k] + 2.f * pxm1[k] + px;  // sD
                const float gy = pym2[k] + 2.f * pym1[k] + py;  // sD
                const float gz = pzm2[k] - pz;                  // dD
                acc += fabsf(gx) + fabsf(gy) + fabsf(gz);
            }
            pxm2[k] = pxm1[k]; pxm1[k] = px;
            pym2[k] = pym1[k]; pym1[k] = py;
            pzm2[k] = pzm1[k]; pzm1[k] = pz;
        }

        __syncthreads();
    }

    // reduce: wave shuffle -> LDS -> one atomic per block
#pragma unroll
    for (int off = 32; off > 0; off >>= 1)
        acc += __shfl_down(acc, off, 64);
    if ((tid & 63) == 0) red[tid >> 6] = acc;
    __syncthreads();
    if (tid == 0) {
        const float s = red[0] + red[1] + red[2] + red[3];
        atomicAdd(out, s * (1.0f / (3.0f * BB * DD * HH * WW)));
    }
}

extern "C" void kernel_launch(void* const* d_in, const int* in_sizes, int n_in,
                              void* d_out, int out_size, void* d_ws, size_t ws_size,
                              hipStream_t stream) {
    const float* moved = (const float*)d_in[0];
    const float* label = (const float*)d_in[1];
    float* out = (float*)d_out;
    (void)in_sizes; (void)n_in; (void)out_size; (void)d_ws; (void)ws_size;

    hipMemsetAsync(out, 0, sizeof(float), stream);
    dim3 grid(HH / TH, DD / DC, BB);    // 24 x 16 x 2 = 768 blocks (3/CU)
    sobel_loss_kernel<<<grid, NTHREADS, 0, stream>>>(moved, label, out);
}